// Round 4
// baseline (192.101 us; speedup 1.0000x reference)
//
#include <hip/hip_runtime.h>
#include <hip/hip_bf16.h>
#include <cstddef>

// x: (8,64,128,128) fp32 | w1:(64,64,1,1) | b1:(64,) | w2:(9,64,5,5)
// tc1:(16,64,1,1) | tc2:(64,16,1,1) | out:(8,64,128,128) fp32
//
// Pipeline (each phase at its own best occupancy):
//   transpose: x -> xT (b,h,w,c) bf16, + fused per-channel sums (part)
//   prep:      Weff hi/lo bf16 MFMA A-fragments + border-gated bias betaG
//   conv:      MFMA GEMM -> wt (8,9,128,128) fp32 (L2-resident, 4.7 MB)
//   blur:      per-(tile,b,8ch) softmax over 9 taps + reflect-pad 3x3 blur,
//              x read in fp32 (exact), consensus tmp computed per-block.

#define B 8
#define C 64
#define HW 128
#define NK 9
#define NT 25
#define LOG2E 1.4426950408889634f

typedef __attribute__((ext_vector_type(8))) short short8;    // 8 bf16
typedef __attribute__((ext_vector_type(4))) float float4v;   // 4 fp32 acc
typedef __attribute__((ext_vector_type(4))) unsigned int uint4v;

__device__ __forceinline__ unsigned short f2bf(float f) {
    unsigned int u = __float_as_uint(f);
    unsigned int r = u + 0x7FFF + ((u >> 16) & 1);   // RNE
    return (unsigned short)(r >> 16);
}
__device__ __forceinline__ float fast_exp2(float x) {   // v_exp_f32: D = 2^S0
    float r;
    asm("v_exp_f32 %0, %1" : "=v"(r) : "v"(x));
    return r;
}
__device__ __forceinline__ float fast_rcp(float x) {
    float r;
    asm("v_rcp_f32 %0, %1" : "=v"(r) : "v"(x));
    return r;
}

// ---------- kernel 1: x (b,c,h,w) fp32 -> xT (b,h,w,c) bf16, + channel sums ----------
__global__ __launch_bounds__(256) void transpose_kernel(const float* __restrict__ x,
                                                        unsigned short* __restrict__ xT,
                                                        float* __restrict__ part) {
    __shared__ float tile[64 * 129];
    const int gi = blockIdx.x, b = blockIdx.y;
    const int tid = threadIdx.x;
    for (int it = 0; it < 8; ++it) {
        const int idx = it * 256 + tid;
        const int cidx = idx >> 5, f4 = idx & 31;
        float4 v = *(const float4*)(x + (((size_t)(b * C + cidx)) * HW + gi) * HW + f4 * 4);
        tile[cidx * 129 + f4 * 4 + 0] = v.x;
        tile[cidx * 129 + f4 * 4 + 1] = v.y;
        tile[cidx * 129 + f4 * 4 + 2] = v.z;
        tile[cidx * 129 + f4 * 4 + 3] = v.w;
    }
    __syncthreads();
    for (int it = 0; it < 4; ++it) {
        const int idx = it * 256 + tid;
        const int gj = idx >> 3, c8 = idx & 7;
        unsigned int p[4];
#pragma unroll
        for (int s = 0; s < 4; ++s) {
            unsigned int lo = f2bf(tile[(c8 * 8 + 2 * s) * 129 + gj]);
            unsigned int hi = f2bf(tile[(c8 * 8 + 2 * s + 1) * 129 + gj]);
            p[s] = lo | (hi << 16);
        }
        uint4v outv = {p[0], p[1], p[2], p[3]};
        *(uint4v*)(xT + (((size_t)b * (HW * HW) + gi * HW + gj) * C + c8 * 8)) = outv;
    }
    if (tid < 64) {
        float s = 0.f;
        for (int g = 0; g < 128; ++g) s += tile[tid * 129 + g];
        atomicAdd(part + tid, s);
    }
}

// ---------- kernel 2: Abuf (LDS-staged Weff GEMV) + betaG ----------
// blocks 0..49: chunk (t, ch) -> 512 A-slots each. block 50: betaG.
__global__ __launch_bounds__(256) void prep_kernel(const float* __restrict__ w1,
                                                   const float* __restrict__ b1,
                                                   const float* __restrict__ w2,
                                                   unsigned short* __restrict__ Abuf,
                                                   float* __restrict__ betaG) {
    if (blockIdx.x < 50) {
        __shared__ float sw2[NK * 64];    // w2[m][cc][t] for fixed t
        __shared__ float sw1[64 * 32];    // w1[cc][ch*32 + j]
        const int chunk = blockIdx.x;
        const int t = chunk >> 1, ch = chunk & 1;
        for (int idx = threadIdx.x; idx < NK * 64; idx += 256) {
            const int m = idx >> 6, cc = idx & 63;
            sw2[idx] = w2[(m * 64 + cc) * NT + t];
        }
        for (int idx = threadIdx.x; idx < 2048; idx += 256) {
            const int cc = idx >> 5, j = idx & 31;
            sw1[idx] = w1[cc * 64 + ch * 32 + j];
        }
        __syncthreads();
        for (int sidx = 0; sidx < 2; ++sidx) {
            const int slot = sidx * 256 + threadIdx.x;   // (quad*16+m)*8+jj
            const int quad = slot >> 7, m = (slot >> 3) & 15, jj = slot & 7;
            unsigned short hi = 0, lo = 0;
            if (m < NK) {
                float s = 0.f;
                for (int cc = 0; cc < 64; ++cc)
                    s += sw2[m * 64 + cc] * sw1[cc * 32 + quad * 8 + jj];
                hi = f2bf(s);
                lo = f2bf(s - __uint_as_float(((unsigned int)hi) << 16));
            }
            Abuf[chunk * 1024 + slot] = hi;
            Abuf[chunk * 1024 + 512 + slot] = lo;
        }
    } else {
        __shared__ float beta_s[NT * NK];
        const int t0 = threadIdx.x;
        if (t0 < NT * NK) {
            const int t = t0 / NK, k = t0 - t * NK;
            float s = 0.f;
            for (int cc = 0; cc < 64; ++cc)
                s += w2[(k * 64 + cc) * NT + t] * b1[cc];
            beta_s[t0] = s;
        }
        __syncthreads();
        if (t0 < 225) {   // (ic,jc,k) border classes
            const int ic = t0 / 45, jc = (t0 / 9) % 5, k = t0 % 9;
            float s = 0.f;
            for (int eh = 0; eh < 5; ++eh) {
                bool rok = (ic == 0) ? (eh >= 2) : (ic == 1) ? (eh >= 1)
                          : (ic == 3) ? (eh <= 3) : (ic == 4) ? (eh <= 2) : true;
                if (!rok) continue;
                for (int ew = 0; ew < 5; ++ew) {
                    bool cok = (jc == 0) ? (ew >= 2) : (jc == 1) ? (ew >= 1)
                              : (jc == 3) ? (ew <= 3) : (jc == 4) ? (ew <= 2) : true;
                    if (cok) s += beta_s[(eh * 5 + ew) * NK + k];
                }
            }
            betaG[t0] = s;
        }
    }
}

// ---------- kernel 3: MFMA conv -> wt (8,9,128,128) fp32 ----------
// 8x16 pixel tiles, 128 threads (2 waves), grid (128,8)=1024 blocks.
// stag: 12x20 halo x 32ch (per half, reused), stride 40 ushorts (16B-aligned,
// quarter-wave-balanced banks). Direct C-layout store (no shuffle).
__global__ __launch_bounds__(128, 3) void conv_kernel(const unsigned short* __restrict__ xT,
                                                      const unsigned short* __restrict__ Abuf,
                                                      const float* __restrict__ betaG,
                                                      float* __restrict__ wt) {
    __shared__ unsigned short stag[240 * 40];   // 19200 B
    __shared__ float bg[225];
    const int b = blockIdx.y;
    const int i0 = (blockIdx.x >> 3) * 8, j0 = (blockIdx.x & 7) * 16;
    const int tid = threadIdx.x, lane = tid & 63, wid = tid >> 6;
    const int n = lane & 15, q = lane >> 4;
    for (int idx = tid; idx < 225; idx += 128) bg[idx] = betaG[idx];

    float4v acc[4];
    const float4v zero4 = {0.f, 0.f, 0.f, 0.f};
#pragma unroll
    for (int g = 0; g < 4; ++g) acc[g] = zero4;

    for (int half = 0; half < 2; ++half) {
        if (half) __syncthreads();   // waves done with half-0 MFMA before restage
        for (int idx = tid; idx < 960; idx += 128) {
            const int pix = idx >> 2, part = idx & 3;
            const int li = pix / 20, lj = pix - li * 20;
            const int gi = i0 + li - 2, gj = j0 + lj - 2;
            uint4v v = {0u, 0u, 0u, 0u};
            if (gi >= 0 && gi < HW && gj >= 0 && gj < HW)
                v = *(const uint4v*)(xT + (((size_t)b * (HW * HW) + gi * HW + gj) * C
                                           + half * 32 + part * 8));
            *(uint4v*)(stag + pix * 40 + part * 8) = v;
        }
        __syncthreads();
        const unsigned short* Ab = Abuf + half * 1024 + lane * 8;
#pragma unroll
        for (int eh = 0; eh < 5; ++eh) {
#pragma unroll
            for (int ew = 0; ew < 5; ++ew) {
                const int t = eh * 5 + ew;
                const short8 ahi = *(const short8*)(Ab + t * 2048);
                const short8 alo = *(const short8*)(Ab + t * 2048 + 512);
#pragma unroll
                for (int g = 0; g < 4; ++g) {
                    const int r = wid * 4 + g;   // pixel row 0..7
                    const short8 bf = *(const short8*)(stag + ((r + eh) * 20 + ew + n) * 40 + q * 8);
                    acc[g] = __builtin_amdgcn_mfma_f32_16x16x32_bf16(ahi, bf, acc[g], 0, 0, 0);
                    acc[g] = __builtin_amdgcn_mfma_f32_16x16x32_bf16(alo, bf, acc[g], 0, 0, 0);
                }
            }
        }
    }
    // store: D[m=q*4+r][col=n]; add border-gated bias
    const int gj = j0 + n;
    const int jc = gj < 2 ? gj : (gj > 125 ? gj - 123 : 2);
#pragma unroll
    for (int g = 0; g < 4; ++g) {
        const int gi = i0 + wid * 4 + g;
        const int ic = gi < 2 ? gi : (gi > 125 ? gi - 123 : 2);
        const float* bgp = &bg[(ic * 5 + jc) * 9];
#pragma unroll
        for (int ridx = 0; ridx < 4; ++ridx) {
            const int m = q * 4 + ridx;
            if (m < NK)
                wt[(((size_t)b * NK + m) * HW + gi) * HW + gj] = acc[g][ridx] + bgp[m];
        }
    }
}

// ---------- kernel 4: softmax over 9 taps + 3x3 reflect blur (exact fp32 x) ----------
// grid (64 tiles, 8b*8cg), 256 thr. LDS: 18x18x8ch fp32 tile + lt8.
__global__ __launch_bounds__(256, 4) void blur_kernel(const float* __restrict__ x,
                                                      const float* __restrict__ wt,
                                                      const float* __restrict__ part,
                                                      const float* __restrict__ tc1,
                                                      const float* __restrict__ tc2,
                                                      float* __restrict__ out) {
    __shared__ float lx[8 * 325];   // [c][18*18] pad->325
    __shared__ float lt8[8];
    const int b = blockIdx.y >> 3, cg = blockIdx.y & 7;
    const int i0 = (blockIdx.x >> 3) * 16, j0 = (blockIdx.x & 7) * 16;
    const int tid = threadIdx.x;
    const int ti = tid >> 4, tj = tid & 15;
    const int gi = i0 + ti, gj = j0 + tj;

    // wave0: consensus tmp for this block's 8 channels
    if (tid < 64) {
        float xcv = part[tid] * (1.f / (B * HW * HW));
        float h = 0.f;
        for (int c = 0; c < 64; ++c) {
            float xcc = __shfl(xcv, c);
            if (tid < 16) h += tc1[tid * 64 + c] * xcc;
        }
        h = fmaxf(h, 0.f);
        float ltv = 0.f;
#pragma unroll
        for (int o = 0; o < 16; ++o) {
            float ho = __shfl(h, o);
            if (tid < 8) ltv += tc2[(cg * 8 + tid) * 16 + o] * ho;
        }
        if (tid < 8) lt8[tid] = fmaxf(ltv, 0.f) * LOG2E;
    }

    // stage 18x18 x 8ch fp32 with reflect mapping
    for (int idx = tid; idx < 2592; idx += 256) {
        const int c = idx / 324, rem = idx - c * 324;
        const int li = rem / 18, lj = rem - li * 18;
        int ri = i0 + li - 1; ri = ri < 0 ? -ri : (ri > 127 ? 254 - ri : ri);
        int rj = j0 + lj - 1; rj = rj < 0 ? -rj : (rj > 127 ? 254 - rj : rj);
        lx[c * 325 + li * 18 + lj] = x[(((size_t)b * C + cg * 8 + c) * HW + ri) * HW + rj];
    }

    // logits for this pixel (shared across the 8 channels)
    float w[NK];
#pragma unroll
    for (int k = 0; k < NK; ++k)
        w[k] = wt[(((size_t)b * NK + k) * HW + gi) * HW + gj];
    float wmax = w[0];
#pragma unroll
    for (int k = 1; k < NK; ++k) wmax = fmaxf(wmax, w[k]);
    float d[NK];
#pragma unroll
    for (int k = 0; k < NK; ++k) d[k] = w[k] - wmax;

    __syncthreads();

    float* outp = out + (((size_t)b * C + cg * 8) * HW + gi) * HW + gj;
#pragma unroll
    for (int cc = 0; cc < 8; ++cc) {
        const float t = lt8[cc];
        const float* lp = lx + cc * 325 + ti * 18 + tj;
        float s = 0.f, o = 0.f;
#pragma unroll
        for (int kh = 0; kh < 3; ++kh) {
#pragma unroll
            for (int kw = 0; kw < 3; ++kw) {
                const float e = fast_exp2(d[kh * 3 + kw] * t);
                const float xv = lp[kh * 18 + kw];
                s += e;
                o = fmaf(e, xv, o);
            }
        }
        outp[(size_t)cc * (HW * HW)] = o * fast_rcp(s);
    }
}

extern "C" void kernel_launch(void* const* d_in, const int* in_sizes, int n_in,
                              void* d_out, int out_size, void* d_ws, size_t ws_size,
                              hipStream_t stream) {
    const float* x   = (const float*)d_in[0];
    const float* w1  = (const float*)d_in[1];
    const float* b1  = (const float*)d_in[2];
    const float* w2  = (const float*)d_in[3];
    const float* tc1 = (const float*)d_in[4];
    const float* tc2 = (const float*)d_in[5];
    float* out = (float*)d_out;

    // workspace layout (bytes)
    char* ws = (char*)d_ws;
    float* part  = (float*)(ws + 0);                       // 64 fl
    unsigned short* Abuf = (unsigned short*)(ws + 1024);   // 51200 ush = 102400 B
    float* betaG = (float*)(ws + 103424);                  // 225 fl
    float* wt    = (float*)(ws + 104448);                  // 1179648 fl = 4718592 B
    unsigned short* xT = (unsigned short*)(ws + 4823040);  // 8.4M ush = 16.8 MB

    hipMemsetAsync(part, 0, 64 * sizeof(float), stream);
    transpose_kernel<<<dim3(HW, B), 256, 0, stream>>>(x, xT, part);
    prep_kernel<<<51, 256, 0, stream>>>(w1, b1, w2, Abuf, betaG);
    conv_kernel<<<dim3(128, B), 128, 0, stream>>>(xT, Abuf, betaG, wt);
    blur_kernel<<<dim3(64, 64), 256, 0, stream>>>(x, wt, part, tc1, tc2, out);
}

// Round 5
// 167.272 us; speedup vs baseline: 1.1484x; 1.1484x over previous
//
#include <hip/hip_runtime.h>
#include <hip/hip_bf16.h>
#include <cstddef>

// x: (8,64,128,128) fp32 | w1:(64,64,1,1) | b1:(64,) | w2:(9,64,5,5)
// tc1:(16,64,1,1) | tc2:(64,16,1,1) | out:(8,64,128,128) fp32
//
// Pipeline:
//   prep:      Weff hi/lo bf16 MFMA A-fragments + border-gated bias betaG
//   transpose: x -> xT (b,h,w,c) bf16, + fused per-channel sums (part)
//   fused:     per 8x16 tile: MFMA conv -> logits (registers) -> intra-wave
//              exchange -> softmax(9) -> 3x3 reflect blur from the SAME LDS
//              stag tile -> out. wt never touches HBM. One barrier per block.

#define B 8
#define C 64
#define HW 128
#define NK 9
#define NT 25
#define LOG2E 1.4426950408889634f
#define PSTR 72   // stag pixel stride in ushorts (64 ch + 8 pad; 144 B, 16B-aligned)

typedef __attribute__((ext_vector_type(8))) short short8;    // 8 bf16
typedef __attribute__((ext_vector_type(4))) float float4v;   // 4 fp32 acc
typedef __attribute__((ext_vector_type(4))) unsigned int uint4v;

__device__ __forceinline__ unsigned short f2bf(float f) {
    unsigned int u = __float_as_uint(f);
    unsigned int r = u + 0x7FFF + ((u >> 16) & 1);   // RNE
    return (unsigned short)(r >> 16);
}
__device__ __forceinline__ float fast_exp2(float x) {   // v_exp_f32: D = 2^S0
    float r;
    asm("v_exp_f32 %0, %1" : "=v"(r) : "v"(x));
    return r;
}
__device__ __forceinline__ float fast_rcp(float x) {
    float r;
    asm("v_rcp_f32 %0, %1" : "=v"(r) : "v"(x));
    return r;
}

// ---------- kernel 1: x (b,c,h,w) fp32 -> xT (b,h,w,c) bf16, + channel sums ----------
__global__ __launch_bounds__(256) void transpose_kernel(const float* __restrict__ x,
                                                        unsigned short* __restrict__ xT,
                                                        float* __restrict__ part) {
    __shared__ float tile[64 * 129];
    const int gi = blockIdx.x, b = blockIdx.y;
    const int tid = threadIdx.x;
    for (int it = 0; it < 8; ++it) {
        const int idx = it * 256 + tid;
        const int cidx = idx >> 5, f4 = idx & 31;
        float4 v = *(const float4*)(x + (((size_t)(b * C + cidx)) * HW + gi) * HW + f4 * 4);
        tile[cidx * 129 + f4 * 4 + 0] = v.x;
        tile[cidx * 129 + f4 * 4 + 1] = v.y;
        tile[cidx * 129 + f4 * 4 + 2] = v.z;
        tile[cidx * 129 + f4 * 4 + 3] = v.w;
    }
    __syncthreads();
    for (int it = 0; it < 4; ++it) {
        const int idx = it * 256 + tid;
        const int gj = idx >> 3, c8 = idx & 7;
        unsigned int p[4];
#pragma unroll
        for (int s = 0; s < 4; ++s) {
            unsigned int lo = f2bf(tile[(c8 * 8 + 2 * s) * 129 + gj]);
            unsigned int hi = f2bf(tile[(c8 * 8 + 2 * s + 1) * 129 + gj]);
            p[s] = lo | (hi << 16);
        }
        uint4v outv = {p[0], p[1], p[2], p[3]};
        *(uint4v*)(xT + (((size_t)b * (HW * HW) + gi * HW + gj) * C + c8 * 8)) = outv;
    }
    if (tid < 64) {
        float s = 0.f;
        for (int g = 0; g < 128; ++g) s += tile[tid * 129 + g];
        atomicAdd(part + tid, s);
    }
}

// ---------- kernel 2: Abuf (LDS-staged Weff GEMV) + betaG ----------
__global__ __launch_bounds__(256) void prep_kernel(const float* __restrict__ w1,
                                                   const float* __restrict__ b1,
                                                   const float* __restrict__ w2,
                                                   unsigned short* __restrict__ Abuf,
                                                   float* __restrict__ betaG) {
    if (blockIdx.x < 50) {
        __shared__ float sw2[NK * 64];    // w2[m][cc][t] for fixed t
        __shared__ float sw1[64 * 32];    // w1[cc][ch*32 + j]
        const int chunk = blockIdx.x;
        const int t = chunk >> 1, ch = chunk & 1;
        for (int idx = threadIdx.x; idx < NK * 64; idx += 256) {
            const int m = idx >> 6, cc = idx & 63;
            sw2[idx] = w2[(m * 64 + cc) * NT + t];
        }
        for (int idx = threadIdx.x; idx < 2048; idx += 256) {
            const int cc = idx >> 5, j = idx & 31;
            sw1[idx] = w1[cc * 64 + ch * 32 + j];
        }
        __syncthreads();
        for (int sidx = 0; sidx < 2; ++sidx) {
            const int slot = sidx * 256 + threadIdx.x;   // (quad*16+m)*8+jj
            const int quad = slot >> 7, m = (slot >> 3) & 15, jj = slot & 7;
            unsigned short hi = 0, lo = 0;
            if (m < NK) {
                float s = 0.f;
                for (int cc = 0; cc < 64; ++cc)
                    s += sw2[m * 64 + cc] * sw1[cc * 32 + quad * 8 + jj];
                hi = f2bf(s);
                lo = f2bf(s - __uint_as_float(((unsigned int)hi) << 16));
            }
            Abuf[chunk * 1024 + slot] = hi;
            Abuf[chunk * 1024 + 512 + slot] = lo;
        }
    } else {
        __shared__ float beta_s[NT * NK];
        const int t0 = threadIdx.x;
        if (t0 < NT * NK) {
            const int t = t0 / NK, k = t0 - t * NK;
            float s = 0.f;
            for (int cc = 0; cc < 64; ++cc)
                s += w2[(k * 64 + cc) * NT + t] * b1[cc];
            beta_s[t0] = s;
        }
        __syncthreads();
        if (t0 < 225) {   // (ic,jc,k) border classes
            const int ic = t0 / 45, jc = (t0 / 9) % 5, k = t0 % 9;
            float s = 0.f;
            for (int eh = 0; eh < 5; ++eh) {
                bool rok = (ic == 0) ? (eh >= 2) : (ic == 1) ? (eh >= 1)
                          : (ic == 3) ? (eh <= 3) : (ic == 4) ? (eh <= 2) : true;
                if (!rok) continue;
                for (int ew = 0; ew < 5; ++ew) {
                    bool cok = (jc == 0) ? (ew >= 2) : (jc == 1) ? (ew >= 1)
                              : (jc == 3) ? (ew <= 3) : (jc == 4) ? (ew <= 2) : true;
                    if (cok) s += beta_s[(eh * 5 + ew) * NK + k];
                }
            }
            betaG[t0] = s;
        }
    }
}

// ---------- kernel 3: fused MFMA conv + softmax + blur ----------
// 8x16 tile, 128 thr (2 waves), grid (128,8)=1024 -> 4 blocks/CU.
// stag: 12x20 halo x 64ch bf16, pixel stride PSTR=72 ush. One barrier.
__global__ __launch_bounds__(128, 2) void fused_kernel(const unsigned short* __restrict__ xT,
                                                       const unsigned short* __restrict__ Abuf,
                                                       const float* __restrict__ betaG,
                                                       const float* __restrict__ part,
                                                       const float* __restrict__ tc1,
                                                       const float* __restrict__ tc2,
                                                       float* __restrict__ out) {
    __shared__ unsigned short stag[240 * PSTR];   // 34560 B
    __shared__ float bg[225];
    __shared__ float lt[C];
    const int b = blockIdx.y;
    const int i0 = (blockIdx.x >> 3) * 8, j0 = (blockIdx.x & 7) * 16;
    const int tid = threadIdx.x, lane = tid & 63, wid = tid >> 6;
    const int n = lane & 15, q = lane >> 4;

    // ---- stage 12x20 halo x 64 ch bf16 (zero pad = conv's y zero-pad) ----
    for (int it = 0; it < 15; ++it) {
        const int idx = it * 128 + tid;         // 1920 tasks, g8-fastest (coalesced 128B)
        const int pix = idx >> 3, g8 = idx & 7;
        const int li = pix / 20, lj = pix - li * 20;
        const int gi = i0 + li - 2, gj = j0 + lj - 2;
        uint4v v = {0u, 0u, 0u, 0u};
        if (gi >= 0 && gi < HW && gj >= 0 && gj < HW)
            v = *(const uint4v*)(xT + (((size_t)b * (HW * HW) + gi * HW + gj) * C + g8 * 8));
        *(uint4v*)(stag + pix * PSTR + g8 * 8) = v;
    }
    for (int idx = tid; idx < 225; idx += 128) bg[idx] = betaG[idx];

    // ---- wave0: consensus lt[c] = relu(tc2 @ relu(tc1 @ xcon)) * log2e ----
    if (wid == 0) {
        float xcv = part[lane] * (1.f / (B * HW * HW));
        float h = 0.f;
        for (int c = 0; c < C; ++c) {
            float xcc = __shfl(xcv, c);
            if (lane < 16) h += tc1[lane * C + c] * xcc;
        }
        h = fmaxf(h, 0.f);
        float ltv = 0.f;
#pragma unroll
        for (int o = 0; o < 16; ++o) {
            float ho = __shfl(h, o);
            ltv += tc2[lane * 16 + o] * ho;
        }
        lt[lane] = fmaxf(ltv, 0.f) * LOG2E;
    }

    __syncthreads();   // stag + bg + lt ready (the ONLY barrier)

    // ---- MFMA conv: 2 halves x 25 taps x 4 row-subtiles x (hi+lo) ----
    float4v acc[4];
    const float4v zero4 = {0.f, 0.f, 0.f, 0.f};
#pragma unroll
    for (int g = 0; g < 4; ++g) acc[g] = zero4;

    for (int half = 0; half < 2; ++half) {
        const unsigned short* Ab = Abuf + half * 1024 + lane * 8;
        const unsigned short* sb = stag + half * 32 + q * 8;
#pragma unroll
        for (int eh = 0; eh < 5; ++eh) {
#pragma unroll
            for (int ew = 0; ew < 5; ++ew) {
                const int t = eh * 5 + ew;
                const short8 ahi = *(const short8*)(Ab + t * 2048);
                const short8 alo = *(const short8*)(Ab + t * 2048 + 512);
#pragma unroll
                for (int g = 0; g < 4; ++g) {
                    const int r = wid * 4 + g;   // pixel row 0..7
                    const short8 bf = *(const short8*)(sb + ((r + eh) * 20 + ew + n) * PSTR);
                    acc[g] = __builtin_amdgcn_mfma_f32_16x16x32_bf16(ahi, bf, acc[g], 0, 0, 0);
                    acc[g] = __builtin_amdgcn_mfma_f32_16x16x32_bf16(alo, bf, acc[g], 0, 0, 0);
                }
            }
        }
    }

    // ---- intra-wave exchange: lane gets all 9 logits of its own pixel ----
    // writer lane (q,n): D[m=q*4+r][col n] of subtile g; reader lane l owns
    // pixel (row wid*4 + (l>>4), col l&15)  ==  row tid>>4, col tid&15.
    const int ti = tid >> 4, tj = tid & 15;
    const int gi = i0 + ti, gj = j0 + tj;
    const int ic = gi < 2 ? gi : (gi > 125 ? gi - 123 : 2);
    const int jc = gj < 2 ? gj : (gj > 125 ? gj - 123 : 2);
    float w[NK];
#pragma unroll
    for (int k = 0; k < NK; ++k) {
        const int src = (k >> 2) * 16 + n;
        const int rr = k & 3;
        float v0 = __shfl(acc[0][rr], src);
        float v1 = __shfl(acc[1][rr], src);
        float v2 = __shfl(acc[2][rr], src);
        float v3 = __shfl(acc[3][rr], src);
        const int g = lane >> 4;
        float v = (g == 0) ? v0 : (g == 1) ? v1 : (g == 2) ? v2 : v3;
        w[k] = v + bg[(ic * 5 + jc) * NK + k];
    }

    // ---- softmax prep (channel-independent shift since lt >= 0) ----
    float wmax = w[0];
#pragma unroll
    for (int k = 1; k < NK; ++k) wmax = fmaxf(wmax, w[k]);
    float d[NK];
#pragma unroll
    for (int k = 0; k < NK; ++k) d[k] = w[k] - wmax;

    // ---- blur tap offsets: reflect maps into stag halo's interior ----
    int rr0 = gi - 1; rr0 = rr0 < 0 ? 1 : rr0;
    int rr2 = gi + 1; rr2 = rr2 > 127 ? 126 : rr2;
    int cc0 = gj - 1; cc0 = cc0 < 0 ? 1 : cc0;
    int cc2 = gj + 1; cc2 = cc2 > 127 ? 126 : cc2;
    const int R[3] = {rr0 - i0 + 2, gi - i0 + 2, rr2 - i0 + 2};
    const int Cc[3] = {cc0 - j0 + 2, gj - j0 + 2, cc2 - j0 + 2};
    int off9[NK];
#pragma unroll
    for (int kh = 0; kh < 3; ++kh)
#pragma unroll
        for (int kw = 0; kw < 3; ++kw)
            off9[kh * 3 + kw] = (R[kh] * 20 + Cc[kw]) * PSTR;

    // ---- epilogue: 8 channel-octets; 9 b128 tap reads each ----
    float* outp = out + ((size_t)b * C * (HW * HW) + gi * HW + gj);
    for (int g8 = 0; g8 < 8; ++g8) {
        const unsigned short* sb2 = stag + g8 * 8;
        uint4v xs[NK];
#pragma unroll
        for (int k = 0; k < NK; ++k) xs[k] = *(const uint4v*)(sb2 + off9[k]);
#pragma unroll
        for (int j = 0; j < 4; ++j) {
            const int c0 = g8 * 8 + j * 2;
            {
                const float t = lt[c0];
                float s = 0.f, o = 0.f;
#pragma unroll
                for (int k = 0; k < NK; ++k) {
                    const float e = fast_exp2(d[k] * t);
                    const float xv = __uint_as_float(xs[k][j] << 16);
                    s += e;
                    o = fmaf(e, xv, o);
                }
                outp[(size_t)c0 * (HW * HW)] = o * fast_rcp(s);
            }
            {
                const float t = lt[c0 + 1];
                float s = 0.f, o = 0.f;
#pragma unroll
                for (int k = 0; k < NK; ++k) {
                    const float e = fast_exp2(d[k] * t);
                    const float xv = __uint_as_float(xs[k][j] & 0xffff0000u);
                    s += e;
                    o = fmaf(e, xv, o);
                }
                outp[(size_t)(c0 + 1) * (HW * HW)] = o * fast_rcp(s);
            }
        }
    }
}

extern "C" void kernel_launch(void* const* d_in, const int* in_sizes, int n_in,
                              void* d_out, int out_size, void* d_ws, size_t ws_size,
                              hipStream_t stream) {
    const float* x   = (const float*)d_in[0];
    const float* w1  = (const float*)d_in[1];
    const float* b1  = (const float*)d_in[2];
    const float* w2  = (const float*)d_in[3];
    const float* tc1 = (const float*)d_in[4];
    const float* tc2 = (const float*)d_in[5];
    float* out = (float*)d_out;

    // workspace layout (bytes)
    char* ws = (char*)d_ws;
    float* part  = (float*)(ws + 0);                       // 64 fl
    unsigned short* Abuf = (unsigned short*)(ws + 1024);   // 51200 ush = 102400 B
    float* betaG = (float*)(ws + 103424);                  // 225 fl
    unsigned short* xT = (unsigned short*)(ws + 104448);   // 8.4M ush = 16.8 MB

    hipMemsetAsync(part, 0, 64 * sizeof(float), stream);
    prep_kernel<<<51, 256, 0, stream>>>(w1, b1, w2, Abuf, betaG);
    transpose_kernel<<<dim3(HW, B), 256, 0, stream>>>(x, xT, part);
    fused_kernel<<<dim3(128, B), 128, 0, stream>>>(xT, Abuf, betaG, part, tc1, tc2, out);
}

// Round 6
// 155.999 us; speedup vs baseline: 1.2314x; 1.0723x over previous
//
#include <hip/hip_runtime.h>
#include <hip/hip_bf16.h>
#include <cstddef>

// x: (8,64,128,128) fp32 | w1:(64,64,1,1) | b1:(64,) | w2:(9,64,5,5)
// tc1:(16,64,1,1) | tc2:(64,16,1,1) | out:(8,64,128,128) fp32
//
// Pipeline:
//   transpose: x -> xT (b,h,w,c) bf16, + fused per-channel sums (part)
//   prep:      Weff hi/lo bf16 MFMA A-fragments + border-gated bias betaG
//   fused:     16x16 tile, 512 thr = 8 waves; wave w = (channel-half w&1,
//              row-group w>>1) K-split -> 16 waves/CU (50% occ). Partial
//              logits combined via small LDS buffer; softmax + 3x3 reflect
//              blur from the SAME stag tile; wt never touches HBM.

#define B 8
#define C 64
#define HW 128
#define NK 9
#define NT 25
#define LOG2E 1.4426950408889634f
#define PSTR 72   // stag pixel stride in ushorts (64 ch + 8 pad; 144 B)

typedef __attribute__((ext_vector_type(8))) short short8;    // 8 bf16
typedef __attribute__((ext_vector_type(4))) float float4v;   // 4 fp32 acc
typedef __attribute__((ext_vector_type(4))) unsigned int uint4v;

__device__ __forceinline__ unsigned short f2bf(float f) {
    unsigned int u = __float_as_uint(f);
    unsigned int r = u + 0x7FFF + ((u >> 16) & 1);   // RNE
    return (unsigned short)(r >> 16);
}
__device__ __forceinline__ float fast_exp2(float x) {   // v_exp_f32: D = 2^S0
    float r;
    asm("v_exp_f32 %0, %1" : "=v"(r) : "v"(x));
    return r;
}
__device__ __forceinline__ float fast_rcp(float x) {
    float r;
    asm("v_rcp_f32 %0, %1" : "=v"(r) : "v"(x));
    return r;
}

// ---------- kernel 1: x (b,c,h,w) fp32 -> xT (b,h,w,c) bf16, + channel sums ----------
__global__ __launch_bounds__(256) void transpose_kernel(const float* __restrict__ x,
                                                        unsigned short* __restrict__ xT,
                                                        float* __restrict__ part) {
    __shared__ float tile[64 * 129];
    const int gi = blockIdx.x, b = blockIdx.y;
    const int tid = threadIdx.x;
    for (int it = 0; it < 8; ++it) {
        const int idx = it * 256 + tid;
        const int cidx = idx >> 5, f4 = idx & 31;
        float4 v = *(const float4*)(x + (((size_t)(b * C + cidx)) * HW + gi) * HW + f4 * 4);
        tile[cidx * 129 + f4 * 4 + 0] = v.x;
        tile[cidx * 129 + f4 * 4 + 1] = v.y;
        tile[cidx * 129 + f4 * 4 + 2] = v.z;
        tile[cidx * 129 + f4 * 4 + 3] = v.w;
    }
    __syncthreads();
    for (int it = 0; it < 4; ++it) {
        const int idx = it * 256 + tid;
        const int gj = idx >> 3, c8 = idx & 7;
        unsigned int p[4];
#pragma unroll
        for (int s = 0; s < 4; ++s) {
            unsigned int lo = f2bf(tile[(c8 * 8 + 2 * s) * 129 + gj]);
            unsigned int hi = f2bf(tile[(c8 * 8 + 2 * s + 1) * 129 + gj]);
            p[s] = lo | (hi << 16);
        }
        uint4v outv = {p[0], p[1], p[2], p[3]};
        *(uint4v*)(xT + (((size_t)b * (HW * HW) + gi * HW + gj) * C + c8 * 8)) = outv;
    }
    if (tid < 64) {
        float s = 0.f;
        for (int g = 0; g < 128; ++g) s += tile[tid * 129 + g];
        atomicAdd(part + tid, s);
    }
}

// ---------- kernel 2: Abuf (LDS-staged Weff GEMV) + betaG ----------
__global__ __launch_bounds__(256) void prep_kernel(const float* __restrict__ w1,
                                                   const float* __restrict__ b1,
                                                   const float* __restrict__ w2,
                                                   unsigned short* __restrict__ Abuf,
                                                   float* __restrict__ betaG) {
    if (blockIdx.x < 50) {
        __shared__ float sw2[NK * 64];    // w2[m][cc][t] for fixed t
        __shared__ float sw1[64 * 32];    // w1[cc][ch*32 + j]
        const int chunk = blockIdx.x;
        const int t = chunk >> 1, ch = chunk & 1;
        for (int idx = threadIdx.x; idx < NK * 64; idx += 256) {
            const int m = idx >> 6, cc = idx & 63;
            sw2[idx] = w2[(m * 64 + cc) * NT + t];
        }
        for (int idx = threadIdx.x; idx < 2048; idx += 256) {
            const int cc = idx >> 5, j = idx & 31;
            sw1[idx] = w1[cc * 64 + ch * 32 + j];
        }
        __syncthreads();
        for (int sidx = 0; sidx < 2; ++sidx) {
            const int slot = sidx * 256 + threadIdx.x;   // (quad*16+m)*8+jj
            const int quad = slot >> 7, m = (slot >> 3) & 15, jj = slot & 7;
            unsigned short hi = 0, lo = 0;
            if (m < NK) {
                float s = 0.f;
                for (int cc = 0; cc < 64; ++cc)
                    s += sw2[m * 64 + cc] * sw1[cc * 32 + quad * 8 + jj];
                hi = f2bf(s);
                lo = f2bf(s - __uint_as_float(((unsigned int)hi) << 16));
            }
            Abuf[chunk * 1024 + slot] = hi;
            Abuf[chunk * 1024 + 512 + slot] = lo;
        }
    } else {
        __shared__ float beta_s[NT * NK];
        const int t0 = threadIdx.x;
        if (t0 < NT * NK) {
            const int t = t0 / NK, k = t0 - t * NK;
            float s = 0.f;
            for (int cc = 0; cc < 64; ++cc)
                s += w2[(k * 64 + cc) * NT + t] * b1[cc];
            beta_s[t0] = s;
        }
        __syncthreads();
        if (t0 < 225) {   // (ic,jc,k) border classes
            const int ic = t0 / 45, jc = (t0 / 9) % 5, k = t0 % 9;
            float s = 0.f;
            for (int eh = 0; eh < 5; ++eh) {
                bool rok = (ic == 0) ? (eh >= 2) : (ic == 1) ? (eh >= 1)
                          : (ic == 3) ? (eh <= 3) : (ic == 4) ? (eh <= 2) : true;
                if (!rok) continue;
                for (int ew = 0; ew < 5; ++ew) {
                    bool cok = (jc == 0) ? (ew >= 2) : (jc == 1) ? (ew >= 1)
                              : (jc == 3) ? (ew <= 3) : (jc == 4) ? (ew <= 2) : true;
                    if (cok) s += beta_s[(eh * 5 + ew) * NK + k];
                }
            }
            betaG[t0] = s;
        }
    }
}

// ---------- kernel 3: fused MFMA conv + softmax + blur, K-split waves ----------
// 16x16 tile, 512 thr (8 waves); wave w: half=w&1, rowg=w>>1 (rows rowg*4..+3).
// LDS: stag 400x72 ush (57.6 KB) + wpart 1280 fl (5 KB) + lt = 63 KB
// -> 2 blocks/CU, 16 waves/CU.
__global__ __launch_bounds__(512, 4) void fused_kernel(const unsigned short* __restrict__ xT,
                                                       const unsigned short* __restrict__ Abuf,
                                                       const float* __restrict__ betaG,
                                                       const float* __restrict__ part,
                                                       const float* __restrict__ tc1,
                                                       const float* __restrict__ tc2,
                                                       float* __restrict__ out) {
    __shared__ unsigned short stag[400 * PSTR];   // 57600 B
    __shared__ float wpart[128 * 10];             // 5120 B (per-pass partial/d)
    __shared__ float lt[C];                       // tmp[c] * log2(e)
    const int b = blockIdx.y;
    const int i0 = (blockIdx.x >> 3) * 16, j0 = (blockIdx.x & 7) * 16;
    const int tid = threadIdx.x, lane = tid & 63, wid = tid >> 6;
    const int n = lane & 15, q = lane >> 4;
    const int rowg = wid >> 1, h = wid & 1;

    // ---- stage 20x20 halo x 64 ch bf16 (zero pad = conv's y zero-pad) ----
    for (int idx = tid; idx < 3200; idx += 512) {
        const int pix = idx >> 3, g8 = idx & 7;
        const int li = pix / 20, lj = pix - li * 20;
        const int gi = i0 + li - 2, gj = j0 + lj - 2;
        uint4v v = {0u, 0u, 0u, 0u};
        if (gi >= 0 && gi < HW && gj >= 0 && gj < HW)
            v = *(const uint4v*)(xT + (((size_t)b * (HW * HW) + gi * HW + gj) * C + g8 * 8));
        *(uint4v*)(stag + pix * PSTR + g8 * 8) = v;
    }

    // ---- wave0: consensus lt[c] = relu(tc2 @ relu(tc1 @ xcon)) * log2e ----
    if (wid == 0) {
        float xcv = part[lane] * (1.f / (B * HW * HW));
        float hh = 0.f;
        for (int c = 0; c < C; ++c) {
            float xcc = __shfl(xcv, c);
            if (lane < 16) hh += tc1[lane * C + c] * xcc;
        }
        hh = fmaxf(hh, 0.f);
        float ltv = 0.f;
#pragma unroll
        for (int o = 0; o < 16; ++o) {
            float ho = __shfl(hh, o);
            ltv += tc2[lane * 16 + o] * ho;
        }
        lt[lane] = fmaxf(ltv, 0.f) * LOG2E;
    }

    // ---- even waves: prefetch gated bias for their post-exchange pixel ----
    const int prow = rowg * 4 + q, pcol = n;
    const int pgi = i0 + prow, pgj = j0 + pcol;
    float bgv[NK];
    if (h == 0) {
        const int ic = pgi < 2 ? pgi : (pgi > 125 ? pgi - 123 : 2);
        const int jc = pgj < 2 ? pgj : (pgj > 125 ? pgj - 123 : 2);
        const float* bp = betaG + (ic * 5 + jc) * NK;
#pragma unroll
        for (int k = 0; k < NK; ++k) bgv[k] = bp[k];
    }

    __syncthreads();   // stag + lt ready

    // ---- MFMA: this wave's half, 25 taps x 4 row-subtiles x (hi+lo) ----
    float4v acc[4];
    const float4v zero4 = {0.f, 0.f, 0.f, 0.f};
#pragma unroll
    for (int g = 0; g < 4; ++g) acc[g] = zero4;

    const unsigned short* Ab = Abuf + h * 1024 + lane * 8;
    const unsigned short* sb = stag + h * 32 + q * 8;
#pragma unroll
    for (int eh = 0; eh < 5; ++eh) {
#pragma unroll
        for (int ew = 0; ew < 5; ++ew) {
            const int t = eh * 5 + ew;
            const short8 ahi = *(const short8*)(Ab + t * 2048);
            const short8 alo = *(const short8*)(Ab + t * 2048 + 512);
#pragma unroll
            for (int g = 0; g < 4; ++g) {
                const int r = rowg * 4 + g;
                const short8 bf = *(const short8*)(sb + ((r + eh) * 20 + ew + n) * PSTR);
                acc[g] = __builtin_amdgcn_mfma_f32_16x16x32_bf16(ahi, bf, acc[g], 0, 0, 0);
                acc[g] = __builtin_amdgcn_mfma_f32_16x16x32_bf16(alo, bf, acc[g], 0, 0, 0);
            }
        }
    }

    // ---- intra-wave exchange: lane -> partial logits of its own pixel ----
    // writer lane (q,n): D[m=q*4+rr][col n] of subtile g; reader lane owns
    // pixel (row rowg*4 + q, col n).
    float wv[NK];
#pragma unroll
    for (int k = 0; k < NK; ++k) {
        const int src = (k >> 2) * 16 + n;
        const int rr = k & 3;
        float v0 = __shfl(acc[0][rr], src);
        float v1 = __shfl(acc[1][rr], src);
        float v2 = __shfl(acc[2][rr], src);
        float v3 = __shfl(acc[3][rr], src);
        wv[k] = (q == 0) ? v0 : (q == 1) ? v1 : (q == 2) ? v2 : v3;
    }

    // ---- two passes over row-group pairs: combine halves, softmax, blur ----
    const int lp = ((rowg & 1) << 6) + lane;   // slot within pass (0..127)
    for (int pg = 0; pg < 2; ++pg) {
        const bool inpass = (rowg >> 1) == pg;
        if (pg) __syncthreads();               // protect wpart reuse
        if (inpass && h == 1) {
#pragma unroll
            for (int k = 0; k < NK; ++k) wpart[lp * 10 + k] = wv[k];
        }
        __syncthreads();
        if (inpass && h == 0) {
            float w9[NK];
            float wmax = -1e30f;
#pragma unroll
            for (int k = 0; k < NK; ++k) {
                w9[k] = wv[k] + wpart[lp * 10 + k] + bgv[k];
                wmax = fmaxf(wmax, w9[k]);
            }
#pragma unroll
            for (int k = 0; k < NK; ++k) wpart[lp * 10 + k] = w9[k] - wmax;
        }
        __syncthreads();
        // blur: 128 px x 8 octets = 1024 tasks -> 2 per thread
#pragma unroll
        for (int s = 0; s < 2; ++s) {
            const int task = tid * 2 + s;
            const int lpx = task >> 3, oct = task & 7;
            const int l6 = lpx & 63;
            const int brow = (2 * pg + (lpx >> 6)) * 4 + (l6 >> 4);
            const int bcol = l6 & 15;
            const int bgi = i0 + brow, bgj = j0 + bcol;
            float dv[NK];
#pragma unroll
            for (int k = 0; k < NK; ++k) dv[k] = wpart[lpx * 10 + k];
            int r0 = bgi - 1; r0 = r0 < 0 ? 1 : r0;
            int r2 = bgi + 1; r2 = r2 > 127 ? 126 : r2;
            int c0 = bgj - 1; c0 = c0 < 0 ? 1 : c0;
            int c2 = bgj + 1; c2 = c2 > 127 ? 126 : c2;
            const int R[3] = {r0 - i0 + 2, bgi - i0 + 2, r2 - i0 + 2};
            const int Cc[3] = {c0 - j0 + 2, bgj - j0 + 2, c2 - j0 + 2};
            const unsigned short* sb2 = stag + oct * 8;
            uint4v xs[NK];
#pragma unroll
            for (int kh = 0; kh < 3; ++kh)
#pragma unroll
                for (int kw = 0; kw < 3; ++kw)
                    xs[kh * 3 + kw] = *(const uint4v*)(sb2 + (R[kh] * 20 + Cc[kw]) * PSTR);
            float* outp = out + (((size_t)b * C + oct * 8) * HW + bgi) * HW + bgj;
#pragma unroll
            for (int jj = 0; jj < 4; ++jj) {
                const float t0 = lt[oct * 8 + jj * 2];
                const float t1 = lt[oct * 8 + jj * 2 + 1];
                float s0 = 0.f, o0 = 0.f, s1 = 0.f, o1 = 0.f;
#pragma unroll
                for (int k = 0; k < NK; ++k) {
                    const unsigned int u = xs[k][jj];
                    const float e0 = fast_exp2(dv[k] * t0);
                    const float e1 = fast_exp2(dv[k] * t1);
                    s0 += e0; o0 = fmaf(e0, __uint_as_float(u << 16), o0);
                    s1 += e1; o1 = fmaf(e1, __uint_as_float(u & 0xffff0000u), o1);
                }
                outp[(size_t)(jj * 2) * (HW * HW)] = o0 * fast_rcp(s0);
                outp[(size_t)(jj * 2 + 1) * (HW * HW)] = o1 * fast_rcp(s1);
            }
        }
    }
}

extern "C" void kernel_launch(void* const* d_in, const int* in_sizes, int n_in,
                              void* d_out, int out_size, void* d_ws, size_t ws_size,
                              hipStream_t stream) {
    const float* x   = (const float*)d_in[0];
    const float* w1  = (const float*)d_in[1];
    const float* b1  = (const float*)d_in[2];
    const float* w2  = (const float*)d_in[3];
    const float* tc1 = (const float*)d_in[4];
    const float* tc2 = (const float*)d_in[5];
    float* out = (float*)d_out;

    // workspace layout (bytes)
    char* ws = (char*)d_ws;
    float* part  = (float*)(ws + 0);                       // 64 fl
    unsigned short* Abuf = (unsigned short*)(ws + 1024);   // 51200 ush = 102400 B
    float* betaG = (float*)(ws + 103424);                  // 225 fl
    unsigned short* xT = (unsigned short*)(ws + 104448);   // 8.4M ush = 16.8 MB

    hipMemsetAsync(part, 0, 64 * sizeof(float), stream);
    prep_kernel<<<51, 256, 0, stream>>>(w1, b1, w2, Abuf, betaG);
    transpose_kernel<<<dim3(HW, B), 256, 0, stream>>>(x, xT, part);
    fused_kernel<<<dim3(64, B), 512, 0, stream>>>(xT, Abuf, betaG, part, tc1, tc2, out);
}

// Round 7
// 148.988 us; speedup vs baseline: 1.2894x; 1.0471x over previous
//
#include <hip/hip_runtime.h>
#include <hip/hip_bf16.h>
#include <cstddef>

// x: (8,64,128,128) fp32 | w1:(64,64,1,1) | b1:(64,) | w2:(9,64,5,5)
// tc1:(16,64,1,1) | tc2:(64,16,1,1) | out:(8,64,128,128) fp32
//
// Pipeline (3 launches):
//   xcon:  per-channel partial sums of x (also warms L3 with x)
//   prep:  Weff hi/lo bf16 MFMA A-fragments + border-gated bias betaG
//   fused: 16x16 tile, 512 thr = 8 waves; wave w = (channel-half w&1,
//          row-group w>>1) K-split. Halo staged DIRECTLY from fp32 x
//          (no transpose kernel). MFMA conv with sliding 8-row B-window
//          (40 ds_read_b128/wave instead of 100) -> logits -> softmax ->
//          3x3 reflect blur from the SAME stag tile -> out.

#define B 8
#define C 64
#define HW 128
#define NK 9
#define NT 25
#define LOG2E 1.4426950408889634f
#define PSTR 72   // stag pixel stride in ushorts (64 ch + 8 pad; 144 B)

typedef __attribute__((ext_vector_type(8))) short short8;    // 8 bf16
typedef __attribute__((ext_vector_type(4))) float float4v;   // 4 fp32 acc
typedef __attribute__((ext_vector_type(4))) unsigned int uint4v;

__device__ __forceinline__ unsigned short f2bf(float f) {
    unsigned int u = __float_as_uint(f);
    unsigned int r = u + 0x7FFF + ((u >> 16) & 1);   // RNE
    return (unsigned short)(r >> 16);
}
__device__ __forceinline__ float fast_exp2(float x) {   // v_exp_f32: D = 2^S0
    float r;
    asm("v_exp_f32 %0, %1" : "=v"(r) : "v"(x));
    return r;
}
__device__ __forceinline__ float fast_rcp(float x) {
    float r;
    asm("v_rcp_f32 %0, %1" : "=v"(r) : "v"(x));
    return r;
}

// ---------- kernel 1: per-channel partial sums (direct store, no atomics) ----------
__global__ __launch_bounds__(256) void xcon_kernel(const float* __restrict__ x,
                                                   float* __restrict__ part) {
    const int c = blockIdx.x >> 2, qb = blockIdx.x & 3;
    float s = 0.f;
    for (int bb = 0; bb < 2; ++bb) {
        const int b = qb * 2 + bb;
        const float4* p = (const float4*)(x + ((size_t)(b * C + c)) * (HW * HW));
        for (int idx = threadIdx.x; idx < (HW * HW) / 4; idx += 256) {
            float4 v = p[idx];
            s += (v.x + v.y) + (v.z + v.w);
        }
    }
    __shared__ float red[256];
    red[threadIdx.x] = s;
    __syncthreads();
    for (int off = 128; off > 0; off >>= 1) {
        if (threadIdx.x < off) red[threadIdx.x] += red[threadIdx.x + off];
        __syncthreads();
    }
    if (threadIdx.x == 0) part[c * 4 + qb] = red[0];
}

// ---------- kernel 2: Abuf (LDS-staged Weff GEMV) + betaG ----------
__global__ __launch_bounds__(256) void prep_kernel(const float* __restrict__ w1,
                                                   const float* __restrict__ b1,
                                                   const float* __restrict__ w2,
                                                   unsigned short* __restrict__ Abuf,
                                                   float* __restrict__ betaG) {
    if (blockIdx.x < 50) {
        __shared__ float sw2[NK * 64];    // w2[m][cc][t] for fixed t
        __shared__ float sw1[64 * 32];    // w1[cc][ch*32 + j]
        const int chunk = blockIdx.x;
        const int t = chunk >> 1, ch = chunk & 1;
        for (int idx = threadIdx.x; idx < NK * 64; idx += 256) {
            const int m = idx >> 6, cc = idx & 63;
            sw2[idx] = w2[(m * 64 + cc) * NT + t];
        }
        for (int idx = threadIdx.x; idx < 2048; idx += 256) {
            const int cc = idx >> 5, j = idx & 31;
            sw1[idx] = w1[cc * 64 + ch * 32 + j];
        }
        __syncthreads();
        for (int sidx = 0; sidx < 2; ++sidx) {
            const int slot = sidx * 256 + threadIdx.x;   // (quad*16+m)*8+jj
            const int quad = slot >> 7, m = (slot >> 3) & 15, jj = slot & 7;
            unsigned short hi = 0, lo = 0;
            if (m < NK) {
                float s = 0.f;
                for (int cc = 0; cc < 64; ++cc)
                    s += sw2[m * 64 + cc] * sw1[cc * 32 + quad * 8 + jj];
                hi = f2bf(s);
                lo = f2bf(s - __uint_as_float(((unsigned int)hi) << 16));
            }
            Abuf[chunk * 1024 + slot] = hi;
            Abuf[chunk * 1024 + 512 + slot] = lo;
        }
    } else {
        __shared__ float beta_s[NT * NK];
        const int t0 = threadIdx.x;
        if (t0 < NT * NK) {
            const int t = t0 / NK, k = t0 - t * NK;
            float s = 0.f;
            for (int cc = 0; cc < 64; ++cc)
                s += w2[(k * 64 + cc) * NT + t] * b1[cc];
            beta_s[t0] = s;
        }
        __syncthreads();
        if (t0 < 225) {   // (ic,jc,k) border classes
            const int ic = t0 / 45, jc = (t0 / 9) % 5, k = t0 % 9;
            float s = 0.f;
            for (int eh = 0; eh < 5; ++eh) {
                bool rok = (ic == 0) ? (eh >= 2) : (ic == 1) ? (eh >= 1)
                          : (ic == 3) ? (eh <= 3) : (ic == 4) ? (eh <= 2) : true;
                if (!rok) continue;
                for (int ew = 0; ew < 5; ++ew) {
                    bool cok = (jc == 0) ? (ew >= 2) : (jc == 1) ? (ew >= 1)
                              : (jc == 3) ? (ew <= 3) : (jc == 4) ? (ew <= 2) : true;
                    if (cok) s += beta_s[(eh * 5 + ew) * NK + k];
                }
            }
            betaG[t0] = s;
        }
    }
}

// ---------- kernel 3: fused MFMA conv + softmax + blur, K-split waves ----------
// 16x16 tile, 512 thr (8 waves); wave w: half=w&1, rowg=w>>1 (rows rowg*4..+3).
// LDS: stag 400x72 ush (57.6 KB) + wpart 1280 fl (5 KB) + lt -> 63 KB,
// 2 blocks/CU, 16 waves/CU. Staging reads x (fp32 NCHW, L3-warm) directly.
__global__ __launch_bounds__(512, 4) void fused_kernel(const float* __restrict__ x,
                                                       const unsigned short* __restrict__ Abuf,
                                                       const float* __restrict__ betaG,
                                                       const float* __restrict__ part,
                                                       const float* __restrict__ tc1,
                                                       const float* __restrict__ tc2,
                                                       float* __restrict__ out) {
    __shared__ unsigned short stag[400 * PSTR];   // 57600 B
    __shared__ float wpart[128 * 10];             // 5120 B (per-pass partial/d)
    __shared__ float lt[C];                       // tmp[c] * log2(e)
    const int b = blockIdx.y;
    const int i0 = (blockIdx.x >> 3) * 16, j0 = (blockIdx.x & 7) * 16;
    const int tid = threadIdx.x, lane = tid & 63, wid = tid >> 6;
    const int n = lane & 15, q = lane >> 4;
    const int rowg = wid >> 1, h = wid & 1;

    // ---- stage 20x20 halo x 64 ch bf16 straight from fp32 x ----
    // task = (ch, row, col-pair): 64*20*10 = 12800, 25 iters/thread.
    for (int idx = tid; idx < 12800; idx += 512) {
        const int ch = idx / 200;
        const int rem = idx - ch * 200;
        const int li = rem / 10, cp = rem - li * 10;
        const int gi = i0 + li - 2;
        const int gj = j0 + cp * 2 - 2;          // even; pair is all-or-nothing
        unsigned int pack = 0u;
        if (gi >= 0 && gi < HW && gj >= 0 && gj <= HW - 2) {
            const float2 v = *(const float2*)(x + (((size_t)(b * C + ch)) * HW + gi) * HW + gj);
            pack = (unsigned int)f2bf(v.x) | ((unsigned int)f2bf(v.y) << 16);
        }
        const int p0 = (li * 20 + cp * 2) * PSTR + ch;
        stag[p0] = (unsigned short)(pack & 0xffffu);
        stag[p0 + PSTR] = (unsigned short)(pack >> 16);
    }

    // ---- wave0: consensus lt[c] = relu(tc2 @ relu(tc1 @ xcon)) * log2e ----
    if (wid == 0) {
        float xcv = (part[lane * 4 + 0] + part[lane * 4 + 1]
                   + part[lane * 4 + 2] + part[lane * 4 + 3]) * (1.f / (B * HW * HW));
        float hh = 0.f;
        for (int c = 0; c < C; ++c) {
            float xcc = __shfl(xcv, c);
            if (lane < 16) hh += tc1[lane * C + c] * xcc;
        }
        hh = fmaxf(hh, 0.f);
        float ltv = 0.f;
#pragma unroll
        for (int o = 0; o < 16; ++o) {
            float ho = __shfl(hh, o);
            ltv += tc2[lane * 16 + o] * ho;
        }
        lt[lane] = fmaxf(ltv, 0.f) * LOG2E;
    }

    // ---- even waves: prefetch gated bias for their post-exchange pixel ----
    const int prow = rowg * 4 + q;
    const int pgi = i0 + prow, pgj = j0 + n;
    float bgv[NK];
    if (h == 0) {
        const int ic = pgi < 2 ? pgi : (pgi > 125 ? pgi - 123 : 2);
        const int jc = pgj < 2 ? pgj : (pgj > 125 ? pgj - 123 : 2);
        const float* bp = betaG + (ic * 5 + jc) * NK;
#pragma unroll
        for (int k = 0; k < NK; ++k) bgv[k] = bp[k];
    }

    __syncthreads();   // stag + lt ready

    // ---- MFMA conv, sliding 8-row window per ew column ----
    float4v acc[4];
    const float4v zero4 = {0.f, 0.f, 0.f, 0.f};
#pragma unroll
    for (int g = 0; g < 4; ++g) acc[g] = zero4;

    const unsigned short* Ab = Abuf + h * 1024 + lane * 8;
    const unsigned short* sb = stag + h * 32 + q * 8;
#pragma unroll
    for (int ew = 0; ew < 5; ++ew) {
        short8 w8[8];   // halo rows rowg*4 .. rowg*4+7 at column ew+n
#pragma unroll
        for (int rr = 0; rr < 8; ++rr)
            w8[rr] = *(const short8*)(sb + ((rowg * 4 + rr) * 20 + ew + n) * PSTR);
#pragma unroll
        for (int eh = 0; eh < 5; ++eh) {
            const int t = eh * 5 + ew;
            const short8 ahi = *(const short8*)(Ab + t * 2048);
            const short8 alo = *(const short8*)(Ab + t * 2048 + 512);
#pragma unroll
            for (int g = 0; g < 4; ++g) {
                acc[g] = __builtin_amdgcn_mfma_f32_16x16x32_bf16(ahi, w8[g + eh], acc[g], 0, 0, 0);
                acc[g] = __builtin_amdgcn_mfma_f32_16x16x32_bf16(alo, w8[g + eh], acc[g], 0, 0, 0);
            }
        }
    }

    // ---- intra-wave exchange: lane -> partial logits of its own pixel ----
    // writer lane (q,n): D[m=q*4+rr][col n] of subtile g; reader lane owns
    // pixel (row rowg*4 + q, col n).
    float wv[NK];
#pragma unroll
    for (int k = 0; k < NK; ++k) {
        const int src = (k >> 2) * 16 + n;
        const int rr = k & 3;
        float v0 = __shfl(acc[0][rr], src);
        float v1 = __shfl(acc[1][rr], src);
        float v2 = __shfl(acc[2][rr], src);
        float v3 = __shfl(acc[3][rr], src);
        wv[k] = (q == 0) ? v0 : (q == 1) ? v1 : (q == 2) ? v2 : v3;
    }

    // ---- two passes over row-group pairs: combine halves, softmax, blur ----
    const int lp = ((rowg & 1) << 6) + lane;   // slot within pass (0..127)
    for (int pg = 0; pg < 2; ++pg) {
        const bool inpass = (rowg >> 1) == pg;
        if (pg) __syncthreads();               // protect wpart reuse
        if (inpass && h == 1) {
#pragma unroll
            for (int k = 0; k < NK; ++k) wpart[lp * 10 + k] = wv[k];
        }
        __syncthreads();
        if (inpass && h == 0) {
            float w9[NK];
            float wmax = -1e30f;
#pragma unroll
            for (int k = 0; k < NK; ++k) {
                w9[k] = wv[k] + wpart[lp * 10 + k] + bgv[k];
                wmax = fmaxf(wmax, w9[k]);
            }
#pragma unroll
            for (int k = 0; k < NK; ++k) wpart[lp * 10 + k] = w9[k] - wmax;
        }
        __syncthreads();
        // blur: 128 px x 8 octets = 1024 tasks -> 2 per thread
#pragma unroll
        for (int s = 0; s < 2; ++s) {
            const int task = tid * 2 + s;
            const int lpx = task >> 3, oct = task & 7;
            const int l6 = lpx & 63;
            const int brow = (2 * pg + (lpx >> 6)) * 4 + (l6 >> 4);
            const int bcol = l6 & 15;
            const int bgi = i0 + brow, bgj = j0 + bcol;
            float dv[NK];
#pragma unroll
            for (int k = 0; k < NK; ++k) dv[k] = wpart[lpx * 10 + k];
            int r0 = bgi - 1; r0 = r0 < 0 ? 1 : r0;
            int r2 = bgi + 1; r2 = r2 > 127 ? 126 : r2;
            int c0 = bgj - 1; c0 = c0 < 0 ? 1 : c0;
            int c2 = bgj + 1; c2 = c2 > 127 ? 126 : c2;
            const int R[3] = {r0 - i0 + 2, bgi - i0 + 2, r2 - i0 + 2};
            const int Cc[3] = {c0 - j0 + 2, bgj - j0 + 2, c2 - j0 + 2};
            const unsigned short* sb2 = stag + oct * 8;
            uint4v xs[NK];
#pragma unroll
            for (int kh = 0; kh < 3; ++kh)
#pragma unroll
                for (int kw = 0; kw < 3; ++kw)
                    xs[kh * 3 + kw] = *(const uint4v*)(sb2 + (R[kh] * 20 + Cc[kw]) * PSTR);
            float* outp = out + (((size_t)b * C + oct * 8) * HW + bgi) * HW + bgj;
#pragma unroll
            for (int jj = 0; jj < 4; ++jj) {
                const float t0 = lt[oct * 8 + jj * 2];
                const float t1 = lt[oct * 8 + jj * 2 + 1];
                float s0 = 0.f, o0 = 0.f, s1 = 0.f, o1 = 0.f;
#pragma unroll
                for (int k = 0; k < NK; ++k) {
                    const unsigned int u = xs[k][jj];
                    const float e0 = fast_exp2(dv[k] * t0);
                    const float e1 = fast_exp2(dv[k] * t1);
                    s0 += e0; o0 = fmaf(e0, __uint_as_float(u << 16), o0);
                    s1 += e1; o1 = fmaf(e1, __uint_as_float(u & 0xffff0000u), o1);
                }
                outp[(size_t)(jj * 2) * (HW * HW)] = o0 * fast_rcp(s0);
                outp[(size_t)(jj * 2 + 1) * (HW * HW)] = o1 * fast_rcp(s1);
            }
        }
    }
}

extern "C" void kernel_launch(void* const* d_in, const int* in_sizes, int n_in,
                              void* d_out, int out_size, void* d_ws, size_t ws_size,
                              hipStream_t stream) {
    const float* x   = (const float*)d_in[0];
    const float* w1  = (const float*)d_in[1];
    const float* b1  = (const float*)d_in[2];
    const float* w2  = (const float*)d_in[3];
    const float* tc1 = (const float*)d_in[4];
    const float* tc2 = (const float*)d_in[5];
    float* out = (float*)d_out;

    // workspace layout (bytes)
    char* ws = (char*)d_ws;
    float* part  = (float*)(ws + 0);                       // 256 fl
    unsigned short* Abuf = (unsigned short*)(ws + 1024);   // 51200 ush = 102400 B
    float* betaG = (float*)(ws + 103424);                  // 225 fl

    xcon_kernel<<<256, 256, 0, stream>>>(x, part);
    prep_kernel<<<51, 256, 0, stream>>>(w1, b1, w2, Abuf, betaG);
    fused_kernel<<<dim3(64, B), 512, 0, stream>>>(x, Abuf, betaG, part, tc1, tc2, out);
}